// Round 8
// baseline (50.601 us; speedup 1.0000x reference)
//
#include <hip/hip_runtime.h>

// NegSamplingWord2Vec, bf16-gather + 2 batch elements per block (MLP A/B):
//   losses[b] = sum_w mask(o_idx!=PAD) * ( softplus(-dot(c,o_w)) +
//                                          sum_k softplus(dot(c,neg_wk)) )
//
// Round-7: bf16 table halved gather bytes; dur scaled with bytes =>
// throughput-bound on beyond-L2 delivery (~3.4 TB/s random 128B lines).
// Open question: fabric ceiling vs concurrency limit. This round doubles
// per-wave MLP (2 batch elems/block -> 14 outstanding 16 B loads/lane).
// If unchanged, we're at the L3 delivery roofline.

#define D_DIM   128
#define W_CTX   10
#define K_NEG   10
#define NROWS   110
#define NROWS_P 112
#define NPASS   7
#define BLK     256

__device__ __forceinline__ float fast_softplus(float x) {
    return fmaxf(x, 0.0f) + __logf(1.0f + __expf(-fabsf(x)));
}

__device__ __forceinline__ unsigned short bf16_rne(float f) {
    unsigned int x = __float_as_uint(f);
    x += 0x7fffu + ((x >> 16) & 1u);
    return (unsigned short)(x >> 16);
}
__device__ __forceinline__ float bflo(unsigned int u) {
    return __uint_as_float(u << 16);
}
__device__ __forceinline__ float bfhi(unsigned int u) {
    return __uint_as_float(u & 0xffff0000u);
}

// ---- kernel 1: f32 table -> bf16 table (RNE), fully streaming ----
__global__ __launch_bounds__(256) void convert_bf16_kernel(
    const float4* __restrict__ src, ushort4* __restrict__ dst, int n4)
{
    const int i = blockIdx.x * 256 + threadIdx.x;
    if (i < n4) {
        const float4 v = src[i];
        ushort4 o;
        o.x = bf16_rne(v.x);
        o.y = bf16_rne(v.y);
        o.z = bf16_rne(v.z);
        o.w = bf16_rne(v.w);
        dst[i] = o;
    }
}

// ---- kernel 2: gather bf16 rows, 2 batch elements per block ----
__global__ __launch_bounds__(BLK) void w2v_bf16x2_kernel(
    const float*          __restrict__ center_vectors,
    const unsigned short* __restrict__ outside_bf16,
    const int*            __restrict__ center_word_index,
    const int*            __restrict__ outside_word_indices,
    const int*            __restrict__ negative_samples,
    float*                __restrict__ out)
{
    const int b0   = blockIdx.x * 2;
    const int tid  = threadIdx.x;
    const int wave = tid >> 6;
    const int lane = tid & 63;
    const int grp  = lane >> 4;   // 0..3 row-group within wave
    const int gl   = lane & 15;   // lane within 16-lane row group

    __shared__ int   s_idx[2][NROWS_P];
    __shared__ float s_part[2][4];

    // ---- stage indices for both batch elements ----
    if (tid < 200) {                              // negatives, coalesced
        const int e = tid / 100, r = tid - e * 100;
        const int w = r / K_NEG, j = r - w * K_NEG;
        s_idx[e][w * 11 + 1 + j] =
            negative_samples[(size_t)(b0 + e) * (W_CTX * K_NEG) + r];
    } else if (tid < 220) {                       // positives
        const int t = tid - 200, e = t / W_CTX, w = t - e * W_CTX;
        s_idx[e][w * 11] = outside_word_indices[(b0 + e) * W_CTX + w];
    } else if (tid < 224) {                       // pad rows -> row 0
        const int t = tid - 220;
        s_idx[t >> 1][NROWS + (t & 1)] = 0;
    }
    __syncthreads();

    // ---- center fragments (elements [gl*8, gl*8+8) of each row) ----
    const int ci0 = center_word_index[b0];
    const int ci1 = center_word_index[b0 + 1];
    const float4* cp0 = reinterpret_cast<const float4*>(
        center_vectors + (size_t)ci0 * D_DIM);
    const float4* cp1 = reinterpret_cast<const float4*>(
        center_vectors + (size_t)ci1 * D_DIM);
    const float4 c00 = cp0[gl * 2], c01 = cp0[gl * 2 + 1];
    const float4 c10 = cp1[gl * 2], c11 = cp1[gl * 2 + 1];

    // ---- row ids + coefficients for both elements ----
    int   idxs[2][NPASS];
    float cfs[2][NPASS];
#pragma unroll
    for (int e = 0; e < 2; ++e) {
#pragma unroll
        for (int p = 0; p < NPASS; ++p) {
            const int r = p * 16 + wave * 4 + grp;   // row in [0,112)
            const int w = r / 11;
            const int j = r - w * 11;
            idxs[e][p] = s_idx[e][r];
            const int oi = s_idx[e][w * 11];
            cfs[e][p] = (oi != 0) ? ((j == 0) ? -1.0f : 1.0f) : 0.0f;
        }
    }

    // ---- issue ALL 14 row loads (16 B each) ----
    uint4 rv[2][NPASS];
#pragma unroll
    for (int e = 0; e < 2; ++e)
#pragma unroll
        for (int p = 0; p < NPASS; ++p)
            rv[e][p] = reinterpret_cast<const uint4*>(
                outside_bf16 + (size_t)idxs[e][p] * D_DIM)[gl];
    // loads cannot cross a may-write-memory asm in either direction
    asm volatile("" ::: "memory");
    __builtin_amdgcn_sched_barrier(0);

    // ---- compute ----
    float acc0 = 0.0f, acc1 = 0.0f;
#pragma unroll
    for (int p = 0; p < NPASS; ++p) {
        float s0 = c00.x * bflo(rv[0][p].x);
        s0 = fmaf(c00.y, bfhi(rv[0][p].x), s0);
        s0 = fmaf(c00.z, bflo(rv[0][p].y), s0);
        s0 = fmaf(c00.w, bfhi(rv[0][p].y), s0);
        s0 = fmaf(c01.x, bflo(rv[0][p].z), s0);
        s0 = fmaf(c01.y, bfhi(rv[0][p].z), s0);
        s0 = fmaf(c01.z, bflo(rv[0][p].w), s0);
        s0 = fmaf(c01.w, bfhi(rv[0][p].w), s0);

        float s1 = c10.x * bflo(rv[1][p].x);
        s1 = fmaf(c10.y, bfhi(rv[1][p].x), s1);
        s1 = fmaf(c10.z, bflo(rv[1][p].y), s1);
        s1 = fmaf(c10.w, bfhi(rv[1][p].y), s1);
        s1 = fmaf(c11.x, bflo(rv[1][p].z), s1);
        s1 = fmaf(c11.y, bfhi(rv[1][p].z), s1);
        s1 = fmaf(c11.z, bflo(rv[1][p].w), s1);
        s1 = fmaf(c11.w, bfhi(rv[1][p].w), s1);

        s0 += __shfl_xor(s0, 8, 64);
        s0 += __shfl_xor(s0, 4, 64);
        s0 += __shfl_xor(s0, 2, 64);
        s0 += __shfl_xor(s0, 1, 64);

        s1 += __shfl_xor(s1, 8, 64);
        s1 += __shfl_xor(s1, 4, 64);
        s1 += __shfl_xor(s1, 2, 64);
        s1 += __shfl_xor(s1, 1, 64);

        acc0 += fabsf(cfs[0][p]) * fast_softplus(cfs[0][p] * s0);
        acc1 += fabsf(cfs[1][p]) * fast_softplus(cfs[1][p] * s1);
    }

    acc0 += __shfl_xor(acc0, 16, 64);
    acc0 += __shfl_xor(acc0, 32, 64);
    acc1 += __shfl_xor(acc1, 16, 64);
    acc1 += __shfl_xor(acc1, 32, 64);

    if (lane == 0) { s_part[0][wave] = acc0; s_part[1][wave] = acc1; }
    __syncthreads();

    if (tid < 2)
        out[b0 + tid] = s_part[tid][0] + s_part[tid][1] +
                        s_part[tid][2] + s_part[tid][3];
}

// ---- fallback (round-3 proven f32 kernel) if ws too small ----
__global__ __launch_bounds__(BLK) void w2v_f32_kernel(
    const float* __restrict__ center_vectors,
    const float* __restrict__ outside_vectors,
    const int*   __restrict__ center_word_index,
    const int*   __restrict__ outside_word_indices,
    const int*   __restrict__ negative_samples,
    float*       __restrict__ out)
{
    const int b    = blockIdx.x;
    const int tid  = threadIdx.x;
    const int wave = tid >> 6;
    const int lane = tid & 63;
    const int grp  = lane >> 4;
    const int gl   = lane & 15;

    __shared__ int   s_idx[NROWS_P];
    __shared__ float s_part[4];

    if (tid < W_CTX) {
        s_idx[tid * 11] = outside_word_indices[b * W_CTX + tid];
    } else if (tid >= 16 && tid < 16 + W_CTX * K_NEG) {
        const int r = tid - 16;
        const int w = r / K_NEG;
        const int j = r - w * K_NEG;
        s_idx[w * 11 + 1 + j] = negative_samples[b * W_CTX * K_NEG + r];
    } else if (tid >= 128 && tid < 128 + (NROWS_P - NROWS)) {
        s_idx[NROWS + (tid - 128)] = 0;
    }
    __syncthreads();

    const int ci = center_word_index[b];
    const float4* cp = reinterpret_cast<const float4*>(
        center_vectors + (size_t)ci * D_DIM);
    const float4 c0 = cp[gl];
    const float4 c1 = cp[16 + gl];

    float acc = 0.0f;
#pragma unroll
    for (int p = 0; p < NPASS; ++p) {
        const int r = p * 16 + wave * 4 + grp;
        const int w = r / 11;
        const int j = r - w * 11;
        const int idx = s_idx[r];
        const int oi = s_idx[w * 11];
        const float cf = (oi != 0) ? ((j == 0) ? -1.0f : 1.0f) : 0.0f;

        const float4* rp = reinterpret_cast<const float4*>(
            outside_vectors + (size_t)idx * D_DIM);
        const float4 a0 = rp[gl];
        const float4 a1 = rp[16 + gl];

        float s = c0.x * a0.x;
        s = fmaf(c0.y, a0.y, s);
        s = fmaf(c0.z, a0.z, s);
        s = fmaf(c0.w, a0.w, s);
        s = fmaf(c1.x, a1.x, s);
        s = fmaf(c1.y, a1.y, s);
        s = fmaf(c1.z, a1.z, s);
        s = fmaf(c1.w, a1.w, s);

        s += __shfl_xor(s, 8, 64);
        s += __shfl_xor(s, 4, 64);
        s += __shfl_xor(s, 2, 64);
        s += __shfl_xor(s, 1, 64);

        acc += fabsf(cf) * fast_softplus(cf * s);
    }

    acc += __shfl_xor(acc, 16, 64);
    acc += __shfl_xor(acc, 32, 64);

    if (lane == 0) s_part[wave] = acc;
    __syncthreads();

    if (tid == 0)
        out[b] = s_part[0] + s_part[1] + s_part[2] + s_part[3];
}

extern "C" void kernel_launch(void* const* d_in, const int* in_sizes, int n_in,
                              void* d_out, int out_size, void* d_ws, size_t ws_size,
                              hipStream_t stream) {
    const float* center_vectors       = (const float*)d_in[0];
    const float* outside_vectors      = (const float*)d_in[1];
    const int*   center_word_index    = (const int*)d_in[2];
    const int*   outside_word_indices = (const int*)d_in[3];
    const int*   negative_samples     = (const int*)d_in[4];
    float*       out                  = (float*)d_out;

    const int batch    = in_sizes[2];             // 8192
    const int n_tokens = in_sizes[1] / D_DIM;     // 100000
    const size_t need  = (size_t)n_tokens * D_DIM * sizeof(unsigned short);

    if (ws_size >= need && (batch & 1) == 0) {
        unsigned short* obf = (unsigned short*)d_ws;
        const int n4 = n_tokens * D_DIM / 4;      // 3.2M float4 groups
        convert_bf16_kernel<<<(n4 + 255) / 256, 256, 0, stream>>>(
            (const float4*)outside_vectors, (ushort4*)obf, n4);
        w2v_bf16x2_kernel<<<batch / 2, BLK, 0, stream>>>(
            center_vectors, obf, center_word_index,
            outside_word_indices, negative_samples, out);
    } else {
        w2v_f32_kernel<<<batch, BLK, 0, stream>>>(
            center_vectors, outside_vectors, center_word_index,
            outside_word_indices, negative_samples, out);
    }
}